// Round 6
// baseline (24408.559 us; speedup 1.0000x reference)
//
#include <hip/hip_runtime.h>
#include <cstdint>
#include <cstddef>

// LowRankRNN: h_{t+1} = h + coef*(-h + J@relu(h) + I_t),  J = G*W - B/N + M u v^T
//
// Persistent kernel, 64 blocks x 512 threads (1 block/CU), J in registers.
// Sync: sign-bit-encoded data IS the flag (x = relu(h) >= 0; x(t) stored with
// sign bit forced to phase enc(t)=(t>>1)&1; decode = clear sign bit; two
// buffers alternate by t&1 so stale data never satisfies a poll).
//
// R6 = R4 + ONE change (R5's replication + batch-8 LDS spin both reverted —
// they regressed: WRITE_SIZE x5.7 from replicated write-through stores, and
// 8-read LDS spin bursts congested the LDS port against the arriving writes):
//
//   The per-step __syncthreads + batch LDS read is replaced by a SEQUENTIAL
//   PER-CHUNK LDS pipeline. Wave w polls its global chunk w, writes it
//   (still encoded) to LDS immediately, then consumes chunks k=0..7 IN ORDER,
//   each behind a single-ds_read_b128 phase-spin, FMA-ing each chunk as it
//   lands. Accumulation order k=0..7 unchanged -> bit-identical numerics.
//   Benefits: no slowest-of-8-waves barrier quantization per step, and the
//   FMA work overlaps chunk-arrival skew. LDS spin = 1 read/round (cheap).
//
// WAR safety without the barrier: wave w overwrites LDS slot (t&1, w) at
// step t+2 only after its global poll of chunk-w@t+2 passed; that requires
// blocks 8w..8w+7 to have published x(t+2)-parts, which requires their
// step-t+1 reduces, which required ALL blocks' x(t+1) publishes, which
// required every wave of THIS block to finish its step-t reduce, i.e. its
// step-t reads of slot (t&1, w). Stale slots always carry the opposite
// phase (init = -0.0f, sign-set, blocks phase-0's sign-clear check).
//
// Global overwrite safety unchanged from R4: publishing x(t+2) requires
// having acquired all of x(t+1), certifying all step-t reads are done.

constexpr int   NN   = 2048;
constexpr int   TT   = 8192;
constexpr float COEF = 0.001f;             // DT/TAU
constexpr float G_   = 2.0f;
constexpr float BOFF = 10.0f / 2048.0f;    // B/N
constexpr float M_   = 1.5f;

constexpr int NBLK = 64;
constexpr int TPB  = 512;   // 8 waves
constexpr int WPB  = TPB / 64;

typedef float f32x4 __attribute__((ext_vector_type(4)));
typedef int   i32x4 __attribute__((ext_vector_type(4)));

__device__ __forceinline__ i32x4 bc(const f32x4 x) { return __builtin_bit_cast(i32x4, x); }
__device__ __forceinline__ f32x4 fc(const i32x4 x) { return __builtin_bit_cast(f32x4, x); }

// buf0 polled first at t=2 expecting sign-SET  -> init sign-clear (waits)
// buf1 polled first at t=1 expecting sign-CLEAR -> init sign-set  (waits)
__global__ void init_xbufs(float* xb) {
  const int i = blockIdx.x * blockDim.x + threadIdx.x;   // 0..NN-1 over grid
  xb[i]      = 0.0f;
  xb[NN + i] = -1.0f;
}

// One LLC-coherent 16B load + waitcnt inside one asm block (consumers are
// ordered by register dataflow; rule-#18 safe).
__device__ __forceinline__ f32x4 poll1(const float* p) {
  f32x4 c;
  asm volatile("global_load_dwordx4 %0, %1, off sc0 sc1\n\t"
               "s_waitcnt vmcnt(0)"
               : "=&v"(c) : "v"(p) : "memory");
  return c;
}

// write-through 16B publish store (visible at LLC; per-dword atomicity)
__device__ __forceinline__ void store_wt(float* p, f32x4 v) {
  asm volatile("global_store_dwordx4 %0, %1, off sc0 sc1"
               :: "v"(p), "v"(v) : "memory");
}

// single-chunk LDS read with its own waitcnt (dataflow-ordered consumers)
__device__ __forceinline__ f32x4 lds_read1(unsigned addr) {
  f32x4 x;
  asm volatile("ds_read_b128 %0, %1\n\t"
               "s_waitcnt lgkmcnt(0)"
               : "=&v"(x) : "v"(addr) : "memory");
  return x;
}
__device__ __forceinline__ void lds_write16(unsigned addr, f32x4 v) {
  asm volatile("ds_write_b128 %0, %1" :: "v"(addr), "v"(v) : "memory");
}

// butterfly helpers — value-identical to p += __shfl_xor(p, m)
template <int CTRL>
__device__ __forceinline__ float xadd_dpp(float v) {
  const int t = __builtin_amdgcn_update_dpp(0, __builtin_bit_cast(int, v),
                                            CTRL, 0xF, 0xF, false);
  return v + __builtin_bit_cast(float, t);
}
template <int PAT>
__device__ __forceinline__ float xadd_swz(float v) {
  const int t = __builtin_amdgcn_ds_swizzle(__builtin_bit_cast(int, v), PAT);
  return v + __builtin_bit_cast(float, t);
}

__global__ __launch_bounds__(TPB, 2)
void rnn_persist(const float* __restrict__ I_t,
                 const float* __restrict__ h0,
                 const float* __restrict__ W,
                 const float* __restrict__ u,
                 const float* __restrict__ v,
                 float* __restrict__ out_h,   // d_out + TT, [TT][NN]
                 float* __restrict__ xbuf)    // 2*NN floats
{
  __shared__ f32x4 xs[2][NN / 4];             // 16 KB, phase-encoded x

  const int tid = threadIdx.x;
  const int l   = tid & 63;
  const int w   = tid >> 6;
  const int gw  = blockIdx.x * WPB + w;           // global wave 0..511
  const int rb  = gw * 4;                         // this wave's 4 rows
  const int cb  = l * 4;                          // column base per 256-chunk

  // ---- J rows rb..rb+3: J[j][k] <-> row rb+j, cols k*256 + 4l
  f32x4 J[4][8];
#pragma unroll
  for (int j = 0; j < 4; ++j) {
    const float mu = M_ * u[rb + j];
#pragma unroll
    for (int k = 0; k < 8; ++k) {
      const int c = k * 256 + cb;
      const f32x4 wv = *(const f32x4*)(W + (size_t)(rb + j) * NN + c);
      const f32x4 vv = *(const f32x4*)(v + c);
      J[j][k] = G_ * wv - BOFF + mu * vv;
    }
  }

  float h[4];
#pragma unroll
  for (int j = 0; j < 4; ++j) h[j] = h0[rb + j];

  const f32x4 zero4 = {0.f, 0.f, 0.f, 0.f};
  const unsigned xs_base = (unsigned)(size_t)(&xs[0][0]);  // LDS byte offset

  // LDS init: both phases sign-SET (-0.0f) so nothing fake-passes phase 0.
  // One barrier here; none in the main loop.
  {
    const f32x4 m0 = {-0.0f, -0.0f, -0.0f, -0.0f};
    xs[0][tid] = m0;
    xs[1][tid] = m0;
    __syncthreads();
  }

  // I_t pipeline: parity-selected regs, issued ~1 step ahead of use
  f32x4 iva = *(const f32x4*)(I_t + rb);              // row 0
  f32x4 ivb = *(const f32x4*)(I_t + (size_t)NN + rb); // row 1 (in flight)

  for (int t = 0; t < TT; ++t) {
    const f32x4 icur4 = (t & 1) ? ivb : iva;
    const int  bsel = t & 1;
    const bool enc  = ((t >> 1) & 1) != 0;      // phase of x(t)

    // ---- acquire this wave's chunk w of x(t), ENCODED (no decode yet)
    f32x4 cenc;
    if (t == 0) {
      const f32x4 hv = *(const f32x4*)(h0 + w * 256 + cb);
      i32x4 b = bc(__builtin_elementwise_max(hv, zero4));
      b &= 0x7fffffff;   // force sign clear (phase 0), incl. any -0.0
      cenc = fc(b);
    } else {
      const float* pb = xbuf + bsel * NN + w * 256 + cb;
      unsigned spins = 0;
      if (enc) {
        for (;;) {  // fresh: all 4 words sign SET
          cenc = poll1(pb);
          const i32x4 b = bc(cenc);
          if (__all(((b.x & b.y) & (b.z & b.w)) < 0)) break;
          if (++spins > (1u << 22)) break;
        }
      } else {
        for (;;) {  // fresh: all 4 words sign CLEAR
          cenc = poll1(pb);
          const i32x4 b = bc(cenc);
          if (__all(((b.x | b.y) | (b.z | b.w)) >= 0)) break;
          if (++spins > (1u << 22)) break;
        }
      }
    }

    // deliver own chunk to LDS immediately — other waves may be waiting on it
    lds_write16(xs_base + bsel * 8192 + w * 1024 + l * 16, cenc);

    // I_t row t+2: a full step of slack before its consumer
    if (t + 2 < TT) {
      const f32x4 nv = *(const f32x4*)(I_t + (size_t)(t + 2) * NN + rb);
      if (t & 1) ivb = nv; else iva = nv;
    }

    // ---- consume chunks k = 0..7 IN ORDER (bit-identical accumulation),
    // each behind a single-read phase-spin; FMA overlaps arrival skew.
    f32x4 p4[4] = {zero4, zero4, zero4, zero4};
    const unsigned rbase = xs_base + bsel * 8192 + l * 16;
#pragma unroll
    for (int k = 0; k < 8; ++k) {
      f32x4 xe;
      unsigned spins = 0;
      for (;;) {
        xe = lds_read1(rbase + k * 1024);
        const i32x4 b = bc(xe);
        if (enc) { if (__all(((b.x & b.y) & (b.z & b.w)) < 0)) break; }
        else     { if (__all(((b.x | b.y) | (b.z | b.w)) >= 0)) break; }
        if (++spins > (1u << 20)) break;
      }
      i32x4 b = bc(xe); b &= 0x7fffffff;          // decode = clear sign
      const f32x4 xd = fc(b);
#pragma unroll
      for (int j = 0; j < 4; ++j)
        p4[j] = __builtin_elementwise_fma(J[j][k], xd, p4[j]);  // v_pk_fma_f32
    }
    float p[4];
#pragma unroll
    for (int j = 0; j < 4; ++j)
      p[j] = (p4[j].x + p4[j].y) + (p4[j].z + p4[j].w);

    // wave allreduce — same pairing order as p += __shfl_xor(p, m), m=32..1
#pragma unroll
    for (int j = 0; j < 4; ++j) {
      p[j] += __shfl_xor(p[j], 32, 64);     // xor32
      p[j] = xadd_swz<0x401F>(p[j]);        // xor16
      p[j] = xadd_dpp<0x128>(p[j]);         // xor8  (row_ror:8)
      p[j] = xadd_swz<0x101F>(p[j]);        // xor4
      p[j] = xadd_dpp<0x4E>(p[j]);          // xor2  (quad_perm [2,3,0,1])
      p[j] = xadd_dpp<0xB1>(p[j]);          // xor1  (quad_perm [1,0,3,2])
    }

    const float ic[4] = {icur4.x, icur4.y, icur4.z, icur4.w};
#pragma unroll
    for (int j = 0; j < 4; ++j)
      h[j] = fmaf(COEF, p[j] + ic[j] - h[j], h[j]);

    // ---- publish x(t+1) = relu(h), sign-encoded: this IS the barrier.
    if (t + 1 < TT) {
      const bool encN = (((t + 1) >> 1) & 1) != 0;
      if (l == 0) {
        i32x4 e;
        e.x = __builtin_bit_cast(int, fmaxf(h[0], 0.f));
        e.y = __builtin_bit_cast(int, fmaxf(h[1], 0.f));
        e.z = __builtin_bit_cast(int, fmaxf(h[2], 0.f));
        e.w = __builtin_bit_cast(int, fmaxf(h[3], 0.f));
        if (encN) e |= 0x80000000; else e &= 0x7fffffff;
        store_wt(xbuf + ((t + 1) & 1) * NN + rb, fc(e));
      }
    }
    // trace store (cached; off the critical path)
    if (l == 0) {
      f32x4 hv; hv.x = h[0]; hv.y = h[1]; hv.z = h[2]; hv.w = h[3];
      *(f32x4*)(out_h + (size_t)t * NN + rb) = hv;
    }
  }
}

__global__ __launch_bounds__(256)
void readout(const float* __restrict__ h_all,
             const float* __restrict__ ro_w,
             const float* __restrict__ ro_b,
             float* __restrict__ y)
{
  __shared__ float red[4];
  const int t   = blockIdx.x;
  const int tid = threadIdx.x;
  const float* h = h_all + (size_t)t * NN;
  const int base = tid * 8;

  const float4 a0 = *(const float4*)(h + base);
  const float4 a1 = *(const float4*)(h + base + 4);
  const float4 w0 = *(const float4*)(ro_w + base);
  const float4 w1 = *(const float4*)(ro_w + base + 4);

  float s = a0.x * w0.x + a0.y * w0.y + a0.z * w0.z + a0.w * w0.w
          + a1.x * w1.x + a1.y * w1.y + a1.z * w1.z + a1.w * w1.w;
#pragma unroll
  for (int m = 32; m >= 1; m >>= 1) s += __shfl_xor(s, m, 64);

  if ((tid & 63) == 0) red[tid >> 6] = s;
  __syncthreads();
  if (tid == 0) y[t] = red[0] + red[1] + red[2] + red[3] + ro_b[0];
}

extern "C" void kernel_launch(void* const* d_in, const int* in_sizes, int n_in,
                              void* d_out, int out_size, void* d_ws, size_t ws_size,
                              hipStream_t stream)
{
  const float* I_t  = (const float*)d_in[0];
  const float* h0   = (const float*)d_in[1];
  const float* W    = (const float*)d_in[2];
  const float* u    = (const float*)d_in[3];
  const float* v    = (const float*)d_in[4];
  const float* ro_w = (const float*)d_in[5];
  const float* ro_b = (const float*)d_in[6];

  float* y    = (float*)d_out;             // [TT]
  float* outh = (float*)d_out + TT;        // [TT][NN]

  float* xbuf = (float*)d_ws;              // 2*NN floats

  init_xbufs<<<NN / TPB, TPB, 0, stream>>>(xbuf);
  rnn_persist<<<NBLK, TPB, 0, stream>>>(I_t, h0, W, u, v, outh, xbuf);
  readout<<<TT, 256, 0, stream>>>(outh, ro_w, ro_b, y);
}

// Round 7
// 19800.009 us; speedup vs baseline: 1.2328x; 1.2328x over previous
//
#include <hip/hip_runtime.h>
#include <cstdint>
#include <cstddef>

// LowRankRNN: h_{t+1} = h + coef*(-h + J@relu(h) + I_t),  J = G*W - B/N + M u v^T
//
// Persistent kernel, 64 blocks x 512 threads (1 block/CU), J in registers.
// Sync: sign-bit-encoded data IS the flag (x = relu(h) >= 0; x(t) stored with
// sign bit forced to phase enc(t)=(t>>1)&1; decode = clear sign bit; two
// buffers alternate by t&1 so stale data never satisfies a poll).
//
// R7 = R4 (best: 16.7ms) + ONE isolated change: REPLICATED PUBLISH (R=8).
//   After the allreduce every lane holds h[], so lanes 0..7 store the same
//   encoded 16B to 8 replica x-buffers — ONE store instruction (8 active
//   lanes, 8 distinct LLC lines), so publish cost on the critical path is
//   unchanged. Block b polls replica b&7: coherent readers per LLC line drop
//   64 -> 8, removing hot-line slice serialization (~20-30cy/reader at 64
//   readers ~ 1300-2000cy/step, the dominant unexplained term in R4).
//   Evidence: R5 (replication + bad LDS-spin) beat R6 (no replication + bad
//   LDS-spin) by 3.1ms despite 5.7x WRITE_SIZE. The barrier + compiler-
//   scheduled LDS reads (R4 structure) are KEPT — both no-barrier LDS-spin
//   variants (R5 batch-8, R6 sequential) regressed: spin loops keep waves
//   active burning issue slots/LDS port, while s_barrier parks them.
//
// Overwrite safety unchanged: publishing x(t+2) requires having acquired all
// of x(t+1), which required every block's step-t barrier, i.e. all step-t
// reads of buffer t&1 are done before anyone can write it again. All
// replicas carry identical values; per-dword store atomicity + per-word
// sign check handle partial arrival.

constexpr int   NN   = 2048;
constexpr int   TT   = 8192;
constexpr float COEF = 0.001f;             // DT/TAU
constexpr float G_   = 2.0f;
constexpr float BOFF = 10.0f / 2048.0f;    // B/N
constexpr float M_   = 1.5f;

constexpr int NBLK = 64;    // 1 block/CU
constexpr int TPB  = 512;   // 8 waves
constexpr int WPB  = TPB / 64;

typedef float f32x4 __attribute__((ext_vector_type(4)));
typedef int   i32x4 __attribute__((ext_vector_type(4)));

__device__ __forceinline__ i32x4 bc(const f32x4 x) { return __builtin_bit_cast(i32x4, x); }
__device__ __forceinline__ f32x4 fc(const i32x4 x) { return __builtin_bit_cast(f32x4, x); }

// Layout: xbuf[replica][phase][NN]. phase0 polled first at t=2 expecting
// sign-SET -> init clear (waits). phase1 polled first at t=1 expecting
// sign-CLEAR -> init set (waits). phase = bit 11 of linear index.
__global__ void init_xbufs(float* xb, int total) {
  const int i = blockIdx.x * blockDim.x + threadIdx.x;
  if (i < total) xb[i] = ((i >> 11) & 1) ? -1.0f : 0.0f;
}

// One LLC-coherent 16B load + waitcnt inside one asm block (consumers are
// ordered by register dataflow; rule-#18 safe).
__device__ __forceinline__ f32x4 poll1(const float* p) {
  f32x4 c;
  asm volatile("global_load_dwordx4 %0, %1, off sc0 sc1\n\t"
               "s_waitcnt vmcnt(0)"
               : "=&v"(c) : "v"(p) : "memory");
  return c;
}

// write-through 16B publish store (visible at LLC; per-dword atomicity)
__device__ __forceinline__ void store_wt(float* p, f32x4 v) {
  asm volatile("global_store_dwordx4 %0, %1, off sc0 sc1"
               :: "v"(p), "v"(v) : "memory");
}

// butterfly helpers — value-identical to p += __shfl_xor(p, m)
template <int CTRL>
__device__ __forceinline__ float xadd_dpp(float v) {
  const int t = __builtin_amdgcn_update_dpp(0, __builtin_bit_cast(int, v),
                                            CTRL, 0xF, 0xF, false);
  return v + __builtin_bit_cast(float, t);
}
template <int PAT>
__device__ __forceinline__ float xadd_swz(float v) {
  const int t = __builtin_amdgcn_ds_swizzle(__builtin_bit_cast(int, v), PAT);
  return v + __builtin_bit_cast(float, t);
}

__global__ __launch_bounds__(TPB, 2)
void rnn_persist(const float* __restrict__ I_t,
                 const float* __restrict__ h0,
                 const float* __restrict__ W,
                 const float* __restrict__ u,
                 const float* __restrict__ v,
                 float* __restrict__ out_h,   // d_out + TT, [TT][NN]
                 float* __restrict__ xbuf,    // R * 2 * NN floats
                 int R)                        // replica count, power of 2
{
  __shared__ f32x4 xs[2][NN / 4];             // 16 KB, double-buffered x

  const int tid = threadIdx.x;
  const int l   = tid & 63;
  const int w   = tid >> 6;
  const int gw  = blockIdx.x * WPB + w;           // global wave 0..511
  const int rb  = gw * 4;                         // this wave's 4 rows
  const int cb  = l * 4;                          // column base per 256-chunk
  const int rrep = blockIdx.x & (R - 1);          // replica this block polls

  // ---- J rows rb..rb+3: J[j][k] <-> row rb+j, cols k*256 + 4l
  f32x4 J[4][8];
#pragma unroll
  for (int j = 0; j < 4; ++j) {
    const float mu = M_ * u[rb + j];
#pragma unroll
    for (int k = 0; k < 8; ++k) {
      const int c = k * 256 + cb;
      const f32x4 wv = *(const f32x4*)(W + (size_t)(rb + j) * NN + c);
      const f32x4 vv = *(const f32x4*)(v + c);
      J[j][k] = G_ * wv - BOFF + mu * vv;
    }
  }

  float h[4];
#pragma unroll
  for (int j = 0; j < 4; ++j) h[j] = h0[rb + j];

  const f32x4 zero4 = {0.f, 0.f, 0.f, 0.f};

  // I_t pipeline: parity-selected regs, issued ~1 step ahead of use
  f32x4 iva = *(const f32x4*)(I_t + rb);              // row 0
  f32x4 ivb = *(const f32x4*)(I_t + (size_t)NN + rb); // row 1 (in flight)

  for (int t = 0; t < TT; ++t) {
    const f32x4 icur4 = (t & 1) ? ivb : iva;
    const int bsel = t & 1;

    // ---- acquire this wave's chunk w of x(t)
    f32x4 c;
    if (t == 0) {
      const f32x4 hv = *(const f32x4*)(h0 + w * 256 + cb);
      c = __builtin_elementwise_max(hv, zero4);   // x(0) = relu(h0)
    } else {
      const bool enc = ((t >> 1) & 1) != 0;       // x(t) stored sign-flipped?
      const float* pb = xbuf + (size_t)rrep * (2 * NN) + bsel * NN + w * 256 + cb;
      unsigned spins = 0;
      if (enc) {
        for (;;) {  // fresh values have sign SET: all 4 words negative
          c = poll1(pb);
          const i32x4 b = bc(c);
          if (__all(((b.x & b.y) & (b.z & b.w)) < 0)) break;
          if (++spins > (1u << 22)) break;        // escape hatch; never hit
        }
      } else {
        for (;;) {  // fresh values have sign CLEAR: all 4 words non-negative
          c = poll1(pb);
          const i32x4 b = bc(c);
          if (__all(((b.x | b.y) | (b.z | b.w)) >= 0)) break;
          if (++spins > (1u << 22)) break;
        }
      }
      i32x4 b = bc(c);
      b &= 0x7fffffff;                            // exact decode: clear sign
      c = __builtin_bit_cast(f32x4, b);
    }

    // ---- issue I_t row t+2 now (full step of slack; same parity slot as t)
    if (t + 2 < TT) {
      const f32x4 nv = *(const f32x4*)(I_t + (size_t)(t + 2) * NN + rb);
      if (t & 1) ivb = nv; else iva = nv;
    }

    xs[bsel][w * 64 + l] = c;                     // ds_write_b128
    __syncthreads();

    // ---- p = J @ x from LDS (values already relu'd + decoded)
    f32x4 p4[4] = {zero4, zero4, zero4, zero4};
#pragma unroll
    for (int k = 0; k < 8; ++k) {
      const f32x4 xv = xs[bsel][k * 64 + l];      // ds_read_b128, conflict-free
#pragma unroll
      for (int j = 0; j < 4; ++j)
        p4[j] = __builtin_elementwise_fma(J[j][k], xv, p4[j]);  // v_pk_fma_f32
    }
    float p[4];
#pragma unroll
    for (int j = 0; j < 4; ++j)
      p[j] = (p4[j].x + p4[j].y) + (p4[j].z + p4[j].w);

    // ---- wave allreduce, same pairing order as p += __shfl_xor(p, m) for
    // m = 32,16,8,4,2,1 (bit-identical), with DPP/swizzle for low latency.
#pragma unroll
    for (int j = 0; j < 4; ++j) {
      p[j] += __shfl_xor(p[j], 32, 64);     // xor32 (ds_permute/permlane)
      p[j] = xadd_swz<0x401F>(p[j]);        // xor16 (ds_swizzle)
      p[j] = xadd_dpp<0x128>(p[j]);         // xor8  (DPP row_ror:8)
      p[j] = xadd_swz<0x101F>(p[j]);        // xor4  (ds_swizzle)
      p[j] = xadd_dpp<0x4E>(p[j]);          // xor2  (DPP quad_perm [2,3,0,1])
      p[j] = xadd_dpp<0xB1>(p[j]);          // xor1  (DPP quad_perm [1,0,3,2])
    }

    const float ic[4] = {icur4.x, icur4.y, icur4.z, icur4.w};
#pragma unroll
    for (int j = 0; j < 4; ++j)
      h[j] = fmaf(COEF, p[j] + ic[j] - h[j], h[j]);

    // ---- publish x(t+1) = relu(h), sign-encoded, to R replicas in ONE
    // store instruction (lanes 0..R-1; all lanes hold h[] after allreduce).
    // This IS the barrier.
    if (t + 1 < TT) {
      const bool encN = (((t + 1) >> 1) & 1) != 0;
      i32x4 e;
      e.x = __builtin_bit_cast(int, fmaxf(h[0], 0.f));
      e.y = __builtin_bit_cast(int, fmaxf(h[1], 0.f));
      e.z = __builtin_bit_cast(int, fmaxf(h[2], 0.f));
      e.w = __builtin_bit_cast(int, fmaxf(h[3], 0.f));
      if (encN) e |= 0x80000000; else e &= 0x7fffffff;
      if (l < R)
        store_wt(xbuf + (size_t)l * (2 * NN) + ((t + 1) & 1) * NN + rb, fc(e));
    }
    // trace store: plain cached store (fast L2 ack; off the critical path)
    if (l == 0) {
      f32x4 hv; hv.x = h[0]; hv.y = h[1]; hv.z = h[2]; hv.w = h[3];
      *(f32x4*)(out_h + (size_t)t * NN + rb) = hv;
    }
  }
}

__global__ __launch_bounds__(256)
void readout(const float* __restrict__ h_all,
             const float* __restrict__ ro_w,
             const float* __restrict__ ro_b,
             float* __restrict__ y)
{
  __shared__ float red[4];
  const int t   = blockIdx.x;
  const int tid = threadIdx.x;
  const float* h = h_all + (size_t)t * NN;
  const int base = tid * 8;

  const float4 a0 = *(const float4*)(h + base);
  const float4 a1 = *(const float4*)(h + base + 4);
  const float4 w0 = *(const float4*)(ro_w + base);
  const float4 w1 = *(const float4*)(ro_w + base + 4);

  float s = a0.x * w0.x + a0.y * w0.y + a0.z * w0.z + a0.w * w0.w
          + a1.x * w1.x + a1.y * w1.y + a1.z * w1.z + a1.w * w1.w;
#pragma unroll
  for (int m = 32; m >= 1; m >>= 1) s += __shfl_xor(s, m, 64);

  if ((tid & 63) == 0) red[tid >> 6] = s;
  __syncthreads();
  if (tid == 0) y[t] = red[0] + red[1] + red[2] + red[3] + ro_b[0];
}

extern "C" void kernel_launch(void* const* d_in, const int* in_sizes, int n_in,
                              void* d_out, int out_size, void* d_ws, size_t ws_size,
                              hipStream_t stream)
{
  const float* I_t  = (const float*)d_in[0];
  const float* h0   = (const float*)d_in[1];
  const float* W    = (const float*)d_in[2];
  const float* u    = (const float*)d_in[3];
  const float* v    = (const float*)d_in[4];
  const float* ro_w = (const float*)d_in[5];
  const float* ro_b = (const float*)d_in[6];

  float* y    = (float*)d_out;             // [TT]
  float* outh = (float*)d_out + TT;        // [TT][NN]

  float* xbuf = (float*)d_ws;

  // replica count: as many as the workspace holds (power of 2, max 8)
  int R = 1;
  if      (ws_size >= (size_t)8 * 2 * NN * 4) R = 8;
  else if (ws_size >= (size_t)4 * 2 * NN * 4) R = 4;
  else if (ws_size >= (size_t)2 * 2 * NN * 4) R = 2;

  const int total = R * 2 * NN;
  init_xbufs<<<(total + TPB - 1) / TPB, TPB, 0, stream>>>(xbuf, total);
  rnn_persist<<<NBLK, TPB, 0, stream>>>(I_t, h0, W, u, v, outh, xbuf, R);
  readout<<<TT, 256, 0, stream>>>(outh, ro_w, ro_b, y);
}

// Round 8
// 16821.518 us; speedup vs baseline: 1.4510x; 1.1771x over previous
//
#include <hip/hip_runtime.h>
#include <cstdint>
#include <cstddef>

// LowRankRNN: h_{t+1} = h + coef*(-h + J@relu(h) + I_t),  J = G*W - B/N + M u v^T
//
// Persistent kernel, 64 blocks x 512 threads (1 block/CU), J in registers.
// Sync: sign-bit-encoded data IS the flag (x = relu(h) >= 0; x(t) stored with
// sign bit forced to phase enc(t)=(t>>1)&1; decode = clear sign bit; two
// buffers alternate by t&1 so stale data never satisfies a poll).
// Wave w polls only its chunk w (1 dwordx4/lane), decodes into LDS, one
// __syncthreads, all waves read x from LDS (R4 structure — the best measured).
//
// R8 = R4 byte-for-byte + ONE change: cache-scope bits on the poll load and
// publish store: "sc0 sc1" -> "sc1".
//   CDNA3/4 encodes SCOPE in sc1:sc0 = {00 CU, 01 SE, 10 DEVICE, 11 SYSTEM}.
//   "sc0 sc1" (system) forced every publish to write through the LLC to DRAM
//   and every poll to fetch from DRAM: R4/R7 counters show x-traffic at HBM
//   (R4 FETCH 331MB ~ inputs + per-step DRAM re-fetch; R7's 8 replicas
//   ballooned WRITE to 1114MB and regressed). Device scope ("sc1" alone,
//   what __hip_atomic AGENT ops use) makes the Infinity Cache the coherence
//   point: cross-XCD visible, no DRAM round trip (~900cy -> ~400cy).
//   Replication reverted to R=1 (hot-line theory refuted by R7).
//
// Overwrite safety unchanged: publishing x(t+2) requires having acquired all
// of x(t+1), which required every block's step-t barrier, i.e. all step-t
// reads of buffer t&1 are done before anyone can write it again. Per-dword
// store atomicity + per-word sign check handle partial arrival.

constexpr int   NN   = 2048;
constexpr int   TT   = 8192;
constexpr float COEF = 0.001f;             // DT/TAU
constexpr float G_   = 2.0f;
constexpr float BOFF = 10.0f / 2048.0f;    // B/N
constexpr float M_   = 1.5f;

constexpr int NBLK = 64;    // 1 block/CU
constexpr int TPB  = 512;   // 8 waves
constexpr int WPB  = TPB / 64;

typedef float f32x4 __attribute__((ext_vector_type(4)));
typedef int   i32x4 __attribute__((ext_vector_type(4)));

__device__ __forceinline__ i32x4 bc(const f32x4 x) { return __builtin_bit_cast(i32x4, x); }
__device__ __forceinline__ f32x4 fc(const i32x4 x) { return __builtin_bit_cast(f32x4, x); }

// buf0 polled first at t=2 expecting sign-SET  -> init sign-clear (waits)
// buf1 polled first at t=1 expecting sign-CLEAR -> init sign-set  (waits)
__global__ void init_xbufs(float* xb) {
  const int i = blockIdx.x * blockDim.x + threadIdx.x;   // 0..NN-1 over grid
  xb[i]      = 0.0f;
  xb[NN + i] = -1.0f;
}

// One DEVICE-scope (LLC-coherent, no DRAM trip) 16B load + waitcnt inside one
// asm block (consumers ordered by register dataflow; rule-#18 safe).
__device__ __forceinline__ f32x4 poll1(const float* p) {
  f32x4 c;
  asm volatile("global_load_dwordx4 %0, %1, off sc1\n\t"
               "s_waitcnt vmcnt(0)"
               : "=&v"(c) : "v"(p) : "memory");
  return c;
}

// DEVICE-scope write-through 16B publish store (visible at LLC; per-dword
// atomicity; does NOT write to DRAM)
__device__ __forceinline__ void store_wt(float* p, f32x4 v) {
  asm volatile("global_store_dwordx4 %0, %1, off sc1"
               :: "v"(p), "v"(v) : "memory");
}

// butterfly helpers — value-identical to p += __shfl_xor(p, m)
template <int CTRL>
__device__ __forceinline__ float xadd_dpp(float v) {
  const int t = __builtin_amdgcn_update_dpp(0, __builtin_bit_cast(int, v),
                                            CTRL, 0xF, 0xF, false);
  return v + __builtin_bit_cast(float, t);
}
template <int PAT>
__device__ __forceinline__ float xadd_swz(float v) {
  const int t = __builtin_amdgcn_ds_swizzle(__builtin_bit_cast(int, v), PAT);
  return v + __builtin_bit_cast(float, t);
}

__global__ __launch_bounds__(TPB, 2)
void rnn_persist(const float* __restrict__ I_t,
                 const float* __restrict__ h0,
                 const float* __restrict__ W,
                 const float* __restrict__ u,
                 const float* __restrict__ v,
                 float* __restrict__ out_h,   // d_out + TT, [TT][NN]
                 float* __restrict__ xbuf)    // 2*NN floats
{
  __shared__ f32x4 xs[2][NN / 4];             // 16 KB, double-buffered x

  const int tid = threadIdx.x;
  const int l   = tid & 63;
  const int w   = tid >> 6;
  const int gw  = blockIdx.x * WPB + w;           // global wave 0..511
  const int rb  = gw * 4;                         // this wave's 4 rows
  const int cb  = l * 4;                          // column base per 256-chunk

  // ---- J rows rb..rb+3: J[j][k] <-> row rb+j, cols k*256 + 4l
  f32x4 J[4][8];
#pragma unroll
  for (int j = 0; j < 4; ++j) {
    const float mu = M_ * u[rb + j];
#pragma unroll
    for (int k = 0; k < 8; ++k) {
      const int c = k * 256 + cb;
      const f32x4 wv = *(const f32x4*)(W + (size_t)(rb + j) * NN + c);
      const f32x4 vv = *(const f32x4*)(v + c);
      J[j][k] = G_ * wv - BOFF + mu * vv;
    }
  }

  float h[4];
#pragma unroll
  for (int j = 0; j < 4; ++j) h[j] = h0[rb + j];

  const f32x4 zero4 = {0.f, 0.f, 0.f, 0.f};

  // I_t pipeline: parity-selected regs, issued ~1 step ahead of use
  f32x4 iva = *(const f32x4*)(I_t + rb);              // row 0
  f32x4 ivb = *(const f32x4*)(I_t + (size_t)NN + rb); // row 1 (in flight)

  for (int t = 0; t < TT; ++t) {
    const f32x4 icur4 = (t & 1) ? ivb : iva;
    const int bsel = t & 1;

    // ---- acquire this wave's chunk w of x(t)
    f32x4 c;
    if (t == 0) {
      const f32x4 hv = *(const f32x4*)(h0 + w * 256 + cb);
      c = __builtin_elementwise_max(hv, zero4);   // x(0) = relu(h0)
    } else {
      const bool enc = ((t >> 1) & 1) != 0;       // x(t) stored sign-flipped?
      const float* pb = xbuf + bsel * NN + w * 256 + cb;
      unsigned spins = 0;
      if (enc) {
        for (;;) {  // fresh values have sign SET: all 4 words negative
          c = poll1(pb);
          const i32x4 b = bc(c);
          if (__all(((b.x & b.y) & (b.z & b.w)) < 0)) break;
          if (++spins > (1u << 22)) break;        // escape hatch; never hit
        }
      } else {
        for (;;) {  // fresh values have sign CLEAR: all 4 words non-negative
          c = poll1(pb);
          const i32x4 b = bc(c);
          if (__all(((b.x | b.y) | (b.z | b.w)) >= 0)) break;
          if (++spins > (1u << 22)) break;
        }
      }
      i32x4 b = bc(c);
      b &= 0x7fffffff;                            // exact decode: clear sign
      c = __builtin_bit_cast(f32x4, b);
    }

    // ---- issue I_t row t+2 now (full step of slack; same parity slot as t)
    if (t + 2 < TT) {
      const f32x4 nv = *(const f32x4*)(I_t + (size_t)(t + 2) * NN + rb);
      if (t & 1) ivb = nv; else iva = nv;
    }

    xs[bsel][w * 64 + l] = c;                     // ds_write_b128
    __syncthreads();

    // ---- p = J @ x from LDS (values already relu'd + decoded)
    f32x4 p4[4] = {zero4, zero4, zero4, zero4};
#pragma unroll
    for (int k = 0; k < 8; ++k) {
      const f32x4 xv = xs[bsel][k * 64 + l];      // ds_read_b128, conflict-free
#pragma unroll
      for (int j = 0; j < 4; ++j)
        p4[j] = __builtin_elementwise_fma(J[j][k], xv, p4[j]);  // v_pk_fma_f32
    }
    float p[4];
#pragma unroll
    for (int j = 0; j < 4; ++j)
      p[j] = (p4[j].x + p4[j].y) + (p4[j].z + p4[j].w);

    // ---- wave allreduce, same pairing order as p += __shfl_xor(p, m) for
    // m = 32,16,8,4,2,1 (bit-identical), with DPP/swizzle for low latency.
#pragma unroll
    for (int j = 0; j < 4; ++j) {
      p[j] += __shfl_xor(p[j], 32, 64);     // xor32 (ds_permute/permlane)
      p[j] = xadd_swz<0x401F>(p[j]);        // xor16 (ds_swizzle)
      p[j] = xadd_dpp<0x128>(p[j]);         // xor8  (DPP row_ror:8)
      p[j] = xadd_swz<0x101F>(p[j]);        // xor4  (ds_swizzle)
      p[j] = xadd_dpp<0x4E>(p[j]);          // xor2  (DPP quad_perm [2,3,0,1])
      p[j] = xadd_dpp<0xB1>(p[j]);          // xor1  (DPP quad_perm [1,0,3,2])
    }

    const float ic[4] = {icur4.x, icur4.y, icur4.z, icur4.w};
#pragma unroll
    for (int j = 0; j < 4; ++j)
      h[j] = fmaf(COEF, p[j] + ic[j] - h[j], h[j]);

    // ---- publish x(t+1) = relu(h), sign-encoded: this IS the barrier.
    if (t + 1 < TT) {
      const bool encN = (((t + 1) >> 1) & 1) != 0;
      if (l == 0) {
        i32x4 e;
        e.x = __builtin_bit_cast(int, fmaxf(h[0], 0.f));
        e.y = __builtin_bit_cast(int, fmaxf(h[1], 0.f));
        e.z = __builtin_bit_cast(int, fmaxf(h[2], 0.f));
        e.w = __builtin_bit_cast(int, fmaxf(h[3], 0.f));
        if (encN) e |= 0x80000000; else e &= 0x7fffffff;
        store_wt(xbuf + ((t + 1) & 1) * NN + rb, fc(e));
      }
    }
    // trace store: plain cached store (fast L2 ack; off the critical path)
    if (l == 0) {
      f32x4 hv; hv.x = h[0]; hv.y = h[1]; hv.z = h[2]; hv.w = h[3];
      *(f32x4*)(out_h + (size_t)t * NN + rb) = hv;
    }
  }
}

__global__ __launch_bounds__(256)
void readout(const float* __restrict__ h_all,
             const float* __restrict__ ro_w,
             const float* __restrict__ ro_b,
             float* __restrict__ y)
{
  __shared__ float red[4];
  const int t   = blockIdx.x;
  const int tid = threadIdx.x;
  const float* h = h_all + (size_t)t * NN;
  const int base = tid * 8;

  const float4 a0 = *(const float4*)(h + base);
  const float4 a1 = *(const float4*)(h + base + 4);
  const float4 w0 = *(const float4*)(ro_w + base);
  const float4 w1 = *(const float4*)(ro_w + base + 4);

  float s = a0.x * w0.x + a0.y * w0.y + a0.z * w0.z + a0.w * w0.w
          + a1.x * w1.x + a1.y * w1.y + a1.z * w1.z + a1.w * w1.w;
#pragma unroll
  for (int m = 32; m >= 1; m >>= 1) s += __shfl_xor(s, m, 64);

  if ((tid & 63) == 0) red[tid >> 6] = s;
  __syncthreads();
  if (tid == 0) y[t] = red[0] + red[1] + red[2] + red[3] + ro_b[0];
}

extern "C" void kernel_launch(void* const* d_in, const int* in_sizes, int n_in,
                              void* d_out, int out_size, void* d_ws, size_t ws_size,
                              hipStream_t stream)
{
  const float* I_t  = (const float*)d_in[0];
  const float* h0   = (const float*)d_in[1];
  const float* W    = (const float*)d_in[2];
  const float* u    = (const float*)d_in[3];
  const float* v    = (const float*)d_in[4];
  const float* ro_w = (const float*)d_in[5];
  const float* ro_b = (const float*)d_in[6];

  float* y    = (float*)d_out;             // [TT]
  float* outh = (float*)d_out + TT;        // [TT][NN]

  float* xbuf = (float*)d_ws;              // 2*NN floats

  init_xbufs<<<NN / TPB, TPB, 0, stream>>>(xbuf);
  rnn_persist<<<NBLK, TPB, 0, stream>>>(I_t, h0, W, u, v, outh, xbuf);
  readout<<<TT, 256, 0, stream>>>(outh, ro_w, ro_b, y);
}